// Round 13
// baseline (359.435 us; speedup 1.0000x reference)
//
#include <hip/hip_runtime.h>

// Problem: B=2, T=2048, D=1024, H=16, dh=64. All inputs/outputs fp32.
// Pipeline (bf16 MFMA internally), 4 dispatches:
//   cvt_all: x,w_qkv,w_proj -> bf16
//   gemm_qkv: qkvb [t][3072] (q cols pre-scaled). BK=64+swizzle, lb(256,4).
//   attn_split: flash attention, 2-way KV-split + R13 FUSED COMBINE:
//               after writing partials, device-scope atomic ticket per
//               (qtile,head,bb); the SECOND split block to finish re-reads
//               both partials (L2-warm) and writes normalized bf16 attnb.
//               Removes the attn_combine kernel (+~10us launch, ~7us kernel).
//   gemm_proj: 64x64 tile, 1024 blocks, 16 waves/CU.
// R12 post-mortem: cooperative mega-kernel measured 687us (grid.sync ~140us
// each) — fusion via cooperative launch is dead; removed entirely.
// Fallback: if ws too small, single-pass attn_mfma (no partials/counters).

typedef __attribute__((ext_vector_type(8))) short s8v;            // bf16 frag (4 VGPR)
typedef __attribute__((ext_vector_type(8))) unsigned short us8;   // 16B of bf16
typedef __attribute__((ext_vector_type(4))) unsigned short us4;   // 8B of bf16
typedef __attribute__((ext_vector_type(4))) float f4v;            // 16x16 C/D
typedef __attribute__((ext_vector_type(16))) float f16v;          // 32x32 C/D
typedef __attribute__((ext_vector_type(4))) unsigned u4v;         // 4x u32 = one A-frag

__device__ __forceinline__ unsigned short f2b(float f) {          // fp32->bf16 RNE
    unsigned u = __builtin_bit_cast(unsigned, f);
    u += 0x7FFFu + ((u >> 16) & 1u);
    return (unsigned short)(u >> 16);
}
// pack two positive floats to bf16x2 by truncation (1 v_perm_b32).
__device__ __forceinline__ unsigned packtrunc(float a, float b, unsigned sel) {
    unsigned r;
    asm("v_perm_b32 %0, %1, %2, %3"
        : "=v"(r)
        : "v"(__builtin_bit_cast(unsigned, b)), "v"(__builtin_bit_cast(unsigned, a)), "s"(sel));
    return r;
}

#if __has_builtin(__builtin_amdgcn_exp2f)
#define EXP2F(x) __builtin_amdgcn_exp2f(x)
#else
#define EXP2F(x) exp2f(x)
#endif

#define QSCALE 0.18033688011112042f   // 0.125 * log2(e)

#define GLD_LDS16(g, l)                                                                        \
    __builtin_amdgcn_global_load_lds((const __attribute__((address_space(1))) unsigned*)(g),   \
                                     (__attribute__((address_space(3))) unsigned*)(l), 16, 0, 0)

// ---------------------------------------------------------------------------
__global__ __launch_bounds__(256) void cvt_all(const float* __restrict__ x,
                                               const float* __restrict__ wq,
                                               const float* __restrict__ wp,
                                               unsigned short* __restrict__ xb,
                                               unsigned short* __restrict__ wqb,
                                               unsigned short* __restrict__ wpb) {
    const int nx = 4096 * 1024 / 4, nq = 3072 * 1024 / 4;
    int i = blockIdx.x * 256 + threadIdx.x;
    const float* s;
    unsigned short* d;
    int j;
    if (i < nx)           { s = x;  d = xb;  j = i; }
    else if (i < nx + nq) { s = wq; d = wqb; j = i - nx; }
    else                  { s = wp; d = wpb; j = i - nx - nq; }
    float4 v = ((const float4*)s)[j];
    ushort4 o;
    o.x = f2b(v.x); o.y = f2b(v.y); o.z = f2b(v.z); o.w = f2b(v.w);
    ((ushort4*)d)[j] = o;
}

// ---------------------------------------------------------------------------
// qkv GEMM: [4096,1024] x [3072,1024]^T -> qkvb [4096][3072] bf16,
// q cols (<1024) pre-scaled by QSCALE. BK=64, XOR chunk swizzle.
// Natural block order: xcd = bx%8 -> B-panel L2-resident. lb(256,4).
__global__ __launch_bounds__(256, 4) void gemm_qkv(const unsigned short* __restrict__ A,
                                                   const unsigned short* __restrict__ B,
                                                   unsigned short* __restrict__ qkvb) {
    __shared__ unsigned short As[128][64];
    __shared__ unsigned short Bs[128][64];
    const int tid = threadIdx.x;
    const int l = tid & 63, w = tid >> 6;
    const int quad = l >> 4, ln = l & 15;
    const int m0 = blockIdx.y * 128, n0 = blockIdx.x * 128;
    const int wm = (w >> 1) * 64, wn = (w & 1) * 64;

    const f4v fz = {0.f, 0.f, 0.f, 0.f};
    f4v acc[4][4];
#pragma unroll
    for (int i = 0; i < 4; ++i)
#pragma unroll
        for (int j = 0; j < 4; ++j) acc[i][j] = fz;

    const int srow = tid >> 3, sc8 = tid & 7;
    const int gcol = ((sc8 ^ (srow & 7)) << 3);             // swizzled global col (shorts)
    const int koff0 = ((quad ^ (ln & 7)) << 3);
    const int koff1 = (((4 + quad) ^ (ln & 7)) << 3);

    const unsigned short* pa = A + (size_t)(m0 + srow) * 1024 + gcol;
    const unsigned short* pb = B + (size_t)(n0 + srow) * 1024 + gcol;

    for (int k0 = 0; k0 < 1024; k0 += 64) {
#pragma unroll
        for (int b = 0; b < 4; ++b) {
            GLD_LDS16(pa + (size_t)32 * b * 1024 + k0, &As[srow + 32 * b][sc8 * 8]);
            GLD_LDS16(pb + (size_t)32 * b * 1024 + k0, &Bs[srow + 32 * b][sc8 * 8]);
        }
        __syncthreads();
#pragma unroll
        for (int ks = 0; ks < 2; ++ks) {
            const int ko = ks ? koff1 : koff0;
            s8v af[4], bf[4];
#pragma unroll
            for (int mt = 0; mt < 4; ++mt) af[mt] = *(const s8v*)&As[wm + mt * 16 + ln][ko];
#pragma unroll
            for (int nt = 0; nt < 4; ++nt) bf[nt] = *(const s8v*)&Bs[wn + nt * 16 + ln][ko];
#pragma unroll
            for (int mt = 0; mt < 4; ++mt)
#pragma unroll
                for (int nt = 0; nt < 4; ++nt)
                    acc[mt][nt] = __builtin_amdgcn_mfma_f32_16x16x32_bf16(af[mt], bf[nt], acc[mt][nt], 0, 0, 0);
        }
        __syncthreads();
    }

#pragma unroll
    for (int mt = 0; mt < 4; ++mt)
#pragma unroll
        for (int nt = 0; nt < 4; ++nt) {
            const int col = n0 + wn + nt * 16 + ln;
            const int row = m0 + wm + mt * 16 + quad * 4;
            const float sc = (col < 1024) ? QSCALE : 1.0f;
#pragma unroll
            for (int r = 0; r < 4; ++r)
                qkvb[(size_t)(row + r) * 3072 + col] = f2b(acc[mt][nt][r] * sc);
        }
}

// ---------------------------------------------------------------------------
// proj GEMM: [4096,1024] x [1024,1024]^T -> fp32. 64x64 tile, BK=64+swizzle.
// Grid (16,64) = 1024 blocks = 4/CU, 4 waves (2x2), LDS 16KB, 16 waves/CU.
__global__ __launch_bounds__(256, 4) void gemm_proj(const unsigned short* __restrict__ A,
                                                    const unsigned short* __restrict__ B,
                                                    float* __restrict__ C) {
    __shared__ unsigned short As[64][64];
    __shared__ unsigned short Bs[64][64];
    const int tid = threadIdx.x;
    const int l = tid & 63, w = tid >> 6;
    const int quad = l >> 4, ln = l & 15;
    const int m0 = blockIdx.y * 64, n0 = blockIdx.x * 64;
    const int wm = (w >> 1) * 32, wn = (w & 1) * 32;

    const f4v fz = {0.f, 0.f, 0.f, 0.f};
    f4v acc[2][2];
#pragma unroll
    for (int i = 0; i < 2; ++i)
#pragma unroll
        for (int j = 0; j < 2; ++j) acc[i][j] = fz;

    const int srow = tid >> 3, sc8 = tid & 7;
    const int gcol = ((sc8 ^ (srow & 7)) << 3);
    const int koff0 = ((quad ^ (ln & 7)) << 3);
    const int koff1 = (((4 + quad) ^ (ln & 7)) << 3);

    for (int k0 = 0; k0 < 1024; k0 += 64) {
#pragma unroll
        for (int b = 0; b < 2; ++b) {
            GLD_LDS16(A + (size_t)(m0 + srow + 32 * b) * 1024 + k0 + gcol, &As[srow + 32 * b][sc8 * 8]);
            GLD_LDS16(B + (size_t)(n0 + srow + 32 * b) * 1024 + k0 + gcol, &Bs[srow + 32 * b][sc8 * 8]);
        }
        __syncthreads();
#pragma unroll
        for (int ks = 0; ks < 2; ++ks) {
            const int ko = ks ? koff1 : koff0;
            s8v af[2], bf[2];
#pragma unroll
            for (int mt = 0; mt < 2; ++mt) af[mt] = *(const s8v*)&As[wm + mt * 16 + ln][ko];
#pragma unroll
            for (int nt = 0; nt < 2; ++nt) bf[nt] = *(const s8v*)&Bs[wn + nt * 16 + ln][ko];
#pragma unroll
            for (int mt = 0; mt < 2; ++mt)
#pragma unroll
                for (int nt = 0; nt < 2; ++nt)
                    acc[mt][nt] = __builtin_amdgcn_mfma_f32_16x16x32_bf16(af[mt], bf[nt], acc[mt][nt], 0, 0, 0);
        }
        __syncthreads();
    }

#pragma unroll
    for (int mt = 0; mt < 2; ++mt)
#pragma unroll
        for (int nt = 0; nt < 2; ++nt) {
            const int row = m0 + wm + mt * 16 + quad * 4;
            const int col = n0 + wn + nt * 16 + ln;
#pragma unroll
            for (int r = 0; r < 4; ++r) C[(size_t)(row + r) * 1024 + col] = acc[mt][nt][r];
        }
}

// ---------------------------------------------------------------------------
// KV-split flash attention + fused last-block combine.
// grid (16 qtiles, 16 heads, 4 = bb*2+sp). Block = 128 q, 4 waves x 32 q.
// After writing UNNORMALIZED partials: __threadfence + device-scope
// atomicAdd on cnt[(bb*16+hh)*16 + qtile]; the SECOND arriver (both splits
// done) re-reads both partials (L2-warm) and writes the bf16 attnb tile.
// cnt must be zeroed per invocation (hipMemsetAsync in kernel_launch).
__global__ __launch_bounds__(256, 4) void attn_split(const unsigned short* __restrict__ qkvb,
                                                     float* __restrict__ opart,
                                                     float* __restrict__ lpart,
                                                     int* __restrict__ cnt,
                                                     unsigned short* __restrict__ attnb) {
    __shared__ unsigned short Ks[2][64][76];   // [buf][s][d]; prologue alias: Q staging
    __shared__ unsigned short Vt[2][64][76];   // [buf][d][s]
    __shared__ int arrive;

    const int tid = threadIdx.x;
    const int l = tid & 63, w = tid >> 6;
    const int m31 = l & 31, h2 = l >> 5;
    const int qw = w * 32;
    const int t0 = blockIdx.x * 128;
    const int hh = blockIdx.y;
    const int bb = blockIdx.z >> 1, sp = blockIdx.z & 1;
    const size_t rowbase = (size_t)bb * 2048;
    const int sbase = sp * 1024;
    const unsigned sel = 0x07060302u;

    // ---- prologue: stage Q coalesced -> dead Ks bufs -> register frags ----
#pragma unroll
    for (int it = 0; it < 4; ++it) {
        const int idx = tid + it * 256;
        const int qr = idx >> 3, qc = (idx & 7) * 8;
        unsigned short* dst = (qr < 64) ? &Ks[0][qr][qc] : &Ks[1][qr - 64][qc];
        *(us8*)dst = *(const us8*)(qkvb + (rowbase + t0 + qr) * 3072 + hh * 64 + qc);
    }
    __syncthreads();
    s8v qf[4];
    {
        const int qrow = qw + m31;   // wave-uniform buf select (waves 0,1 vs 2,3)
#pragma unroll
        for (int k4 = 0; k4 < 4; ++k4)
            qf[k4] = (qrow < 64) ? *(const s8v*)&Ks[0][qrow][k4 * 16 + h2 * 8]
                                 : *(const s8v*)&Ks[1][qrow - 64][k4 * 16 + h2 * 8];
    }
    __syncthreads();   // Q fully consumed before tile-0 staging overwrites Ks

    // staging coords: K rows (b128), V 4-row x 4-col transpose chunks
    const int r0 = tid >> 3, c0 = (tid & 7) * 8;
    const int va = tid >> 4, vc = tid & 15;   // s-group 4*va, d-group 4*vc

    f16v zz;
#pragma unroll
    for (int i = 0; i < 16; ++i) zz[i] = 0.f;
    f16v oacc[2];
    oacc[0] = zz; oacc[1] = zz;
    float lsum = 0.f;

    // tile 0: global -> regs -> buf0
    us8 kreg0 = *(const us8*)(qkvb + (rowbase + sbase + r0) * 3072 + 1024 + hh * 64 + c0);
    us8 kreg1 = *(const us8*)(qkvb + (rowbase + sbase + r0 + 32) * 3072 + 1024 + hh * 64 + c0);
    us4 vreg[4];
#pragma unroll
    for (int j = 0; j < 4; ++j)
        vreg[j] = *(const us4*)(qkvb + (rowbase + sbase + 4 * va + j) * 3072 + 2048 + hh * 64 + 4 * vc);
    *(us8*)&Ks[0][r0][c0] = kreg0;
    *(us8*)&Ks[0][r0 + 32][c0] = kreg1;
#pragma unroll
    for (int dd = 0; dd < 4; ++dd) {
        unsigned lo = (unsigned)vreg[0][dd] | ((unsigned)vreg[1][dd] << 16);
        unsigned hi = (unsigned)vreg[2][dd] | ((unsigned)vreg[3][dd] << 16);
        uint2 pk2; pk2.x = lo; pk2.y = hi;
        *(uint2*)&Vt[0][4 * vc + dd][4 * va] = pk2;   // Vt[d][s0..s0+3]
    }

    for (int i = 0; i < 16; ++i) {
        const int cur = i & 1;
        __syncthreads();   // buf[cur] ready; prior reads of buf[1-cur] drained

        if (i + 1 < 16) {  // issue next tile's loads; compute body covers latency
            const size_t sn = rowbase + sbase + (i + 1) * 64;
            kreg0 = *(const us8*)(qkvb + (sn + r0) * 3072 + 1024 + hh * 64 + c0);
            kreg1 = *(const us8*)(qkvb + (sn + r0 + 32) * 3072 + 1024 + hh * 64 + c0);
#pragma unroll
            for (int j = 0; j < 4; ++j)
                vreg[j] = *(const us4*)(qkvb + (sn + 4 * va + j) * 3072 + 2048 + hh * 64 + 4 * vc);
        }

        // per st-half: QK^T -> exp2 -> pack -> permlane -> PV  (sacc live = 16)
#pragma unroll
        for (int st = 0; st < 2; ++st) {
            f16v sacc = zz;
            __builtin_amdgcn_s_setprio(1);
#pragma unroll
            for (int k4 = 0; k4 < 4; ++k4) {
                s8v kf = *(const s8v*)&Ks[cur][st * 32 + m31][k4 * 16 + h2 * 8];
                sacc = __builtin_amdgcn_mfma_f32_32x32x16_bf16(kf, qf[k4], sacc, 0, 0, 0);
            }
            __builtin_amdgcn_s_setprio(0);
            unsigned wv[4][2];
#pragma unroll
            for (int g = 0; g < 4; ++g) {
                float p0 = EXP2F(sacc[g * 4 + 0]);
                float p1 = EXP2F(sacc[g * 4 + 1]);
                float p2 = EXP2F(sacc[g * 4 + 2]);
                float p3 = EXP2F(sacc[g * 4 + 3]);
                lsum += (p0 + p1) + (p2 + p3);
                wv[g][0] = packtrunc(p0, p1, sel);
                wv[g][1] = packtrunc(p2, p3, sel);
            }
            __builtin_amdgcn_s_setprio(1);
#pragma unroll
            for (int e = 0; e < 2; ++e) {
                auto ra = __builtin_amdgcn_permlane32_swap(wv[2 * e][0], wv[2 * e + 1][0], false, false);
                auto rb = __builtin_amdgcn_permlane32_swap(wv[2 * e][1], wv[2 * e + 1][1], false, false);
                u4v t;
                t[0] = ra[0]; t[1] = rb[0];   // j0..3 (source low half)
                t[2] = ra[1]; t[3] = rb[1];   // j4..7 (source high half)
                s8v pf = __builtin_bit_cast(s8v, t);
                const int k2 = 2 * st + e;
#pragma unroll
                for (int nt = 0; nt < 2; ++nt) {
                    s8v vfr = *(const s8v*)&Vt[cur][nt * 32 + m31][k2 * 16 + h2 * 8];
                    oacc[nt] = __builtin_amdgcn_mfma_f32_32x32x16_bf16(pf, vfr, oacc[nt], 0, 0, 0);
                }
            }
            __builtin_amdgcn_s_setprio(0);
        }

        if (i + 1 < 16) {  // stage tile i+1 into the other buffer (tail; no barrier)
            *(us8*)&Ks[1 - cur][r0][c0] = kreg0;
            *(us8*)&Ks[1 - cur][r0 + 32][c0] = kreg1;
#pragma unroll
            for (int dd = 0; dd < 4; ++dd) {
                unsigned lo = (unsigned)vreg[0][dd] | ((unsigned)vreg[1][dd] << 16);
                unsigned hi = (unsigned)vreg[2][dd] | ((unsigned)vreg[3][dd] << 16);
                uint2 pk2; pk2.x = lo; pk2.y = hi;
                *(uint2*)&Vt[1 - cur][4 * vc + dd][4 * va] = pk2;
            }
        }
    }

    // partial l per q (lanes l and l+32 hold halves of the same q-row)
    lsum += __shfl_xor(lsum, 32, 64);
    if (h2 == 0)
        lpart[((size_t)sp * 4096 + rowbase + t0 + qw + m31) * 16 + hh] = lsum;

    // UNNORMALIZED fp32 partial O.  col d = m31 (+32*nt), row q = 8g+4h2+r
    float* op = opart + (size_t)sp * 4096 * 1024;
#pragma unroll
    for (int nt = 0; nt < 2; ++nt)
#pragma unroll
        for (int g = 0; g < 4; ++g)
#pragma unroll
            for (int r = 0; r < 4; ++r) {
                const int qrow = 8 * g + 4 * h2 + r;
                op[(rowbase + t0 + qw + qrow) * 1024 + hh * 64 + nt * 32 + m31] = oacc[nt][g * 4 + r];
            }

    // ---- fused combine: second split to arrive merges both partials ----
    __threadfence();   // release: partial stores visible device-wide
    if (tid == 0) {
        const int ci = (bb * 16 + hh) * 16 + (t0 >> 7);
        arrive = atomicAdd(&cnt[ci], 1);   // device scope by default
    }
    __syncthreads();
    if (arrive == 1) {
        __threadfence();   // acquire: other split's partials visible
        const float* o0 = opart;
        const float* o1 = opart + (size_t)4096 * 1024;
#pragma unroll
        for (int it = 0; it < 8; ++it) {
            const int chunk = tid + it * 256;          // 0..2047: 128 rows x 16 f4
            const int r = chunk >> 4, cc = chunk & 15;
            const size_t row = rowbase + t0 + r;
            const size_t fi = row * 256 + hh * 16 + cc;
            float4 a = ((const float4*)o0)[fi];
            float4 b = ((const float4*)o1)[fi];
            float ls = lpart[row * 16 + hh] + lpart[((size_t)4096 + row) * 16 + hh];
            float s = 1.001955f / ls;   // (1+2^-9) compensates P truncation bias
            ushort4 o;
            o.x = f2b((a.x + b.x) * s);
            o.y = f2b((a.y + b.y) * s);
            o.z = f2b((a.z + b.z) * s);
            o.w = f2b((a.w + b.w) * s);
            ((ushort4*)attnb)[fi] = o;
        }
    }
}

// ---------------------------------------------------------------------------
// Fallback single-pass attention (normalizes in-kernel). Used when ws_size
// can't hold the split partials.
__global__ __launch_bounds__(256) void attn_mfma(const unsigned short* __restrict__ qkvb,
                                                 unsigned short* __restrict__ attnb) {
    __shared__ unsigned short Ks[2][64][76];
    __shared__ unsigned short Vt[2][64][76];
    __shared__ float lred[128];

    const int tid = threadIdx.x;
    const int l = tid & 63, w = tid >> 6;
    const int m31 = l & 31, h2 = l >> 5;
    const int qw = w * 32;
    const int t0 = blockIdx.x * 128;
    const int hh = blockIdx.y, bb = blockIdx.z;
    const size_t rowbase = (size_t)bb * 2048;
    const unsigned sel = 0x07060302u;

#pragma unroll
    for (int it = 0; it < 4; ++it) {
        const int idx = tid + it * 256;
        const int qr = idx >> 3, qc = (idx & 7) * 8;
        unsigned short* dst = (qr < 64) ? &Ks[0][qr][qc] : &Ks[1][qr - 64][qc];
        *(us8*)dst = *(const us8*)(qkvb + (rowbase + t0 + qr) * 3072 + hh * 64 + qc);
    }
    __syncthreads();
    s8v qf[4];
    {
        const int qrow = qw + m31;
#pragma unroll
        for (int k4 = 0; k4 < 4; ++k4)
            qf[k4] = (qrow < 64) ? *(const s8v*)&Ks[0][qrow][k4 * 16 + h2 * 8]
                                 : *(const s8v*)&Ks[1][qrow - 64][k4 * 16 + h2 * 8];
    }
    __syncthreads();

    const int r0 = tid >> 3, c0 = (tid & 7) * 8;
    const int va = tid >> 4, vc = tid & 15;

    f16v zz;
#pragma unroll
    for (int i = 0; i < 16; ++i) zz[i] = 0.f;
    f16v oacc[2];
    oacc[0] = zz; oacc[1] = zz;
    float lsum = 0.f;

    us8 kreg0 = *(const us8*)(qkvb + (rowbase + r0) * 3072 + 1024 + hh * 64 + c0);
    us8 kreg1 = *(const us8*)(qkvb + (rowbase + r0 + 32) * 3072 + 1024 + hh * 64 + c0);
    us4 vreg[4];
#pragma unroll
    for (int j = 0; j < 4; ++j)
        vreg[j] = *(const us4*)(qkvb + (rowbase + 4 * va + j) * 3072 + 2048 + hh * 64 + 4 * vc);
    *(us8*)&Ks[0][r0][c0] = kreg0;
    *(us8*)&Ks[0][r0 + 32][c0] = kreg1;
#pragma unroll
    for (int dd = 0; dd < 4; ++dd) {
        unsigned lo = (unsigned)vreg[0][dd] | ((unsigned)vreg[1][dd] << 16);
        unsigned hi = (unsigned)vreg[2][dd] | ((unsigned)vreg[3][dd] << 16);
        uint2 pk2; pk2.x = lo; pk2.y = hi;
        *(uint2*)&Vt[0][4 * vc + dd][4 * va] = pk2;
    }

    for (int i = 0; i < 32; ++i) {
        const int cur = i & 1;
        __syncthreads();

        if (i + 1 < 32) {
            const int sn = (i + 1) * 64;
            kreg0 = *(const us8*)(qkvb + (rowbase + sn + r0) * 3072 + 1024 + hh * 64 + c0);
            kreg1 = *(const us8*)(qkvb + (rowbase + sn + r0 + 32) * 3072 + 1024 + hh * 64 + c0);
#pragma unroll
            for (int j = 0; j < 4; ++j)
                vreg[j] = *(const us4*)(qkvb + (rowbase + sn + 4 * va + j) * 3072 + 2048 + hh * 64 + 4 * vc);
        }

        f16v sacc[2];
        sacc[0] = zz; sacc[1] = zz;
#pragma unroll
        for (int k4 = 0; k4 < 4; ++k4) {
#pragma unroll
            for (int st = 0; st < 2; ++st) {
                s8v kf = *(const s8v*)&Ks[cur][st * 32 + m31][k4 * 16 + h2 * 8];
                sacc[st] = __builtin_amdgcn_mfma_f32_32x32x16_bf16(kf, qf[k4], sacc[st], 0, 0, 0);
            }
        }

        unsigned wv[2][4][2];
#pragma unroll
        for (int st = 0; st < 2; ++st)
#pragma unroll
            for (int g = 0; g < 4; ++g) {
                float p0 = EXP2F(sacc[st][g * 4 + 0]);
                float p1 = EXP2F(sacc[st][g * 4 + 1]);
                float p2 = EXP2F(sacc[st][g * 4 + 2]);
                float p3 = EXP2F(sacc[st][g * 4 + 3]);
                lsum += (p0 + p1) + (p2 + p3);
                wv[st][g][0] = packtrunc(p0, p1, sel);
                wv[st][g][1] = packtrunc(p2, p3, sel);
            }

        s8v pf[4];
#pragma unroll
        for (int st = 0; st < 2; ++st)
#pragma unroll
            for (int e = 0; e < 2; ++e) {
                auto ra = __builtin_amdgcn_permlane32_swap(wv[st][2 * e][0], wv[st][2 * e + 1][0], false, false);
                auto rb = __builtin_amdgcn_permlane32_swap(wv[st][2 * e][1], wv[st][2 * e + 1][1], false, false);
                u4v t;
                t[0] = ra[0]; t[1] = rb[0];
                t[2] = ra[1]; t[3] = rb[1];
                pf[2 * st + e] = __builtin_bit_cast(s8v, t);
            }

#pragma unroll
        for (int k2 = 0; k2 < 4; ++k2) {
#pragma unroll
            for (int nt = 0; nt < 2; ++nt) {
                s8v vfr = *(const s8v*)&Vt[cur][nt * 32 + m31][k2 * 16 + h2 * 8];
                oacc[nt] = __builtin_amdgcn_mfma_f32_32x32x16_bf16(pf[k2], vfr, oacc[nt], 0, 0, 0);
            }
        }

        if (i + 1 < 32) {
            *(us8*)&Ks[1 - cur][r0][c0] = kreg0;
            *(us8*)&Ks[1 - cur][r0 + 32][c0] = kreg1;
#pragma unroll
            for (int dd = 0; dd < 4; ++dd) {
                unsigned lo = (unsigned)vreg[0][dd] | ((unsigned)vreg[1][dd] << 16);
                unsigned hi = (unsigned)vreg[2][dd] | ((unsigned)vreg[3][dd] << 16);
                uint2 pk2; pk2.x = lo; pk2.y = hi;
                *(uint2*)&Vt[1 - cur][4 * vc + dd][4 * va] = pk2;
            }
        }
    }

    lsum += __shfl_xor(lsum, 32, 64);
    lred[qw + m31] = lsum;
    float inv[16];
#pragma unroll
    for (int g = 0; g < 4; ++g)
#pragma unroll
        for (int r = 0; r < 4; ++r)
            inv[g * 4 + r] = 1.001955f / lred[qw + 8 * g + 4 * h2 + r];

#pragma unroll
    for (int nt = 0; nt < 2; ++nt)
#pragma unroll
        for (int g = 0; g < 4; ++g)
#pragma unroll
            for (int r = 0; r < 4; ++r) {
                const int qrow = 8 * g + 4 * h2 + r;
                float o = oacc[nt][g * 4 + r] * inv[g * 4 + r];
                attnb[(rowbase + t0 + qw + qrow) * 1024 + hh * 64 + nt * 32 + m31] = f2b(o);
            }
}

// ---------------------------------------------------------------------------
extern "C" void kernel_launch(void* const* d_in, const int* in_sizes, int n_in,
                              void* d_out, int out_size, void* d_ws, size_t ws_size,
                              hipStream_t stream) {
    const float* x      = (const float*)d_in[0];   // [4096,1024]
    const float* w_qkv  = (const float*)d_in[1];   // [3072,1024]
    const float* w_proj = (const float*)d_in[2];   // [1024,1024]
    float* out = (float*)d_out;

    char* p = (char*)d_ws;
    unsigned short* xb    = (unsigned short*)p;  p += (size_t)4096 * 1024 * 2;
    unsigned short* wqb   = (unsigned short*)p;  p += (size_t)3072 * 1024 * 2;
    unsigned short* wpb   = (unsigned short*)p;  p += (size_t)1024 * 1024 * 2;
    unsigned short* qkvb  = (unsigned short*)p;  p += (size_t)4096 * 3072 * 2;
    unsigned short* attnb = (unsigned short*)p;  p += (size_t)4096 * 1024 * 2;
    float* opart = (float*)p;  p += (size_t)2 * 4096 * 1024 * 4;   // 32 MB
    float* lpart = (float*)p;  p += (size_t)2 * 4096 * 16 * 4;     // 0.5 MB
    int*   cnt   = (int*)p;    p += (size_t)512 * 4;               // 2 KB tickets
    const size_t need = (size_t)(p - (char*)d_ws);

    cvt_all<<<8192, 256, 0, stream>>>(x, w_qkv, w_proj, xb, wqb, wpb);

    gemm_qkv<<<dim3(3072 / 128, 4096 / 128), 256, 0, stream>>>(xb, wqb, qkvb);

    if (ws_size >= need) {
        hipMemsetAsync(cnt, 0, 512 * 4, stream);   // reset tickets (capturable)
        attn_split<<<dim3(2048 / 128, 16, 4), 256, 0, stream>>>(qkvb, opart, lpart, cnt, attnb);
    } else {
        attn_mfma<<<dim3(2048 / 128, 16, 2), 256, 0, stream>>>(qkvb, attnb);
    }

    gemm_proj<<<dim3(1024 / 64, 4096 / 64), 256, 0, stream>>>(attnb, wpb, out);
}

// Round 14
// 176.185 us; speedup vs baseline: 2.0401x; 2.0401x over previous
//
#include <hip/hip_runtime.h>

// Problem: B=2, T=2048, D=1024, H=16, dh=64. All inputs/outputs fp32.
// FINAL (R10-verified, 177.5us): 5-dispatch pipeline, bf16 MFMA internally.
//   cvt_all: x,w_qkv,w_proj -> bf16
//   gemm_qkv: qkvb [t][3072] (q cols pre-scaled). BK=64+swizzle, natural
//             block order (bx%8 L2 partition), lb(256,4) reg diet.
//   attn_split: flash attention, 2-way KV-split, 4 blocks/CU (regs<=128).
//   attn_combine: attnb = f2b((O0+O1) * 1.001955/(l0+l1)).
//   gemm_proj: 64x64 tile, 1024 blocks, 16 waves/CU.
// Fusion attempts all measured WORSE and are removed:
//   R8 combine-into-proj A-staging: re-read fp32 partials 16x  -> +30us
//   R12 cooperative mega-kernel: grid.sync ~140us each         -> +510us
//   R13 atomic-ticket fused combine: device fences (L2 wb/inv) -> +182us
// MI355X lesson: kernel boundaries are the CHEAP sync; device-wide ordering
// primitives (grid.sync / __threadfence) cost O(100us) on 8 non-coherent L2s.
// Fallback: if ws too small for the 32.5MB partials, single-pass attn_mfma.

typedef __attribute__((ext_vector_type(8))) short s8v;            // bf16 frag (4 VGPR)
typedef __attribute__((ext_vector_type(8))) unsigned short us8;   // 16B of bf16
typedef __attribute__((ext_vector_type(4))) unsigned short us4;   // 8B of bf16
typedef __attribute__((ext_vector_type(4))) float f4v;            // 16x16 C/D
typedef __attribute__((ext_vector_type(16))) float f16v;          // 32x32 C/D
typedef __attribute__((ext_vector_type(4))) unsigned u4v;         // 4x u32 = one A-frag

__device__ __forceinline__ unsigned short f2b(float f) {          // fp32->bf16 RNE
    unsigned u = __builtin_bit_cast(unsigned, f);
    u += 0x7FFFu + ((u >> 16) & 1u);
    return (unsigned short)(u >> 16);
}
// pack two positive floats to bf16x2 by truncation (1 v_perm_b32).
__device__ __forceinline__ unsigned packtrunc(float a, float b, unsigned sel) {
    unsigned r;
    asm("v_perm_b32 %0, %1, %2, %3"
        : "=v"(r)
        : "v"(__builtin_bit_cast(unsigned, b)), "v"(__builtin_bit_cast(unsigned, a)), "s"(sel));
    return r;
}

#if __has_builtin(__builtin_amdgcn_exp2f)
#define EXP2F(x) __builtin_amdgcn_exp2f(x)
#else
#define EXP2F(x) exp2f(x)
#endif

#define QSCALE 0.18033688011112042f   // 0.125 * log2(e)

// ---------------------------------------------------------------------------
__global__ __launch_bounds__(256) void cvt_all(const float* __restrict__ x,
                                               const float* __restrict__ wq,
                                               const float* __restrict__ wp,
                                               unsigned short* __restrict__ xb,
                                               unsigned short* __restrict__ wqb,
                                               unsigned short* __restrict__ wpb) {
    const int nx = 4096 * 1024 / 4, nq = 3072 * 1024 / 4;
    int i = blockIdx.x * 256 + threadIdx.x;
    const float* s;
    unsigned short* d;
    int j;
    if (i < nx)           { s = x;  d = xb;  j = i; }
    else if (i < nx + nq) { s = wq; d = wqb; j = i - nx; }
    else                  { s = wp; d = wpb; j = i - nx - nq; }
    float4 v = ((const float4*)s)[j];
    ushort4 o;
    o.x = f2b(v.x); o.y = f2b(v.y); o.z = f2b(v.z); o.w = f2b(v.w);
    ((ushort4*)d)[j] = o;
}

// ---------------------------------------------------------------------------
#define GLD_LDS16(g, l)                                                                        \
    __builtin_amdgcn_global_load_lds((const __attribute__((address_space(1))) unsigned*)(g),   \
                                     (__attribute__((address_space(3))) unsigned*)(l), 16, 0, 0)

// qkv GEMM: [4096,1024] x [3072,1024]^T -> qkvb [4096][3072] bf16,
// q cols (<1024) pre-scaled by QSCALE. BK=64, XOR chunk swizzle:
// logical 16B-chunk c of row r stored at column c ^ (r&7).
// Natural block order: xcd = bx%8 (24%8==0) -> 3 fixed n-cols per XCD,
// B-panel L2-resident. lb(256,4): force <=128 regs -> 16 waves/CU.
__global__ __launch_bounds__(256, 4) void gemm_qkv(const unsigned short* __restrict__ A,
                                                   const unsigned short* __restrict__ B,
                                                   unsigned short* __restrict__ qkvb) {
    __shared__ unsigned short As[128][64];
    __shared__ unsigned short Bs[128][64];
    const int tid = threadIdx.x;
    const int l = tid & 63, w = tid >> 6;
    const int quad = l >> 4, ln = l & 15;
    const int m0 = blockIdx.y * 128, n0 = blockIdx.x * 128;
    const int wm = (w >> 1) * 64, wn = (w & 1) * 64;

    const f4v fz = {0.f, 0.f, 0.f, 0.f};
    f4v acc[4][4];
#pragma unroll
    for (int i = 0; i < 4; ++i)
#pragma unroll
        for (int j = 0; j < 4; ++j) acc[i][j] = fz;

    const int srow = tid >> 3, sc8 = tid & 7;
    const int gcol = ((sc8 ^ (srow & 7)) << 3);             // swizzled global col (shorts)
    const int koff0 = ((quad ^ (ln & 7)) << 3);
    const int koff1 = (((4 + quad) ^ (ln & 7)) << 3);

    const unsigned short* pa = A + (size_t)(m0 + srow) * 1024 + gcol;
    const unsigned short* pb = B + (size_t)(n0 + srow) * 1024 + gcol;

    for (int k0 = 0; k0 < 1024; k0 += 64) {
#pragma unroll
        for (int b = 0; b < 4; ++b) {
            GLD_LDS16(pa + (size_t)32 * b * 1024 + k0, &As[srow + 32 * b][sc8 * 8]);
            GLD_LDS16(pb + (size_t)32 * b * 1024 + k0, &Bs[srow + 32 * b][sc8 * 8]);
        }
        __syncthreads();
#pragma unroll
        for (int ks = 0; ks < 2; ++ks) {
            const int ko = ks ? koff1 : koff0;
            s8v af[4], bf[4];
#pragma unroll
            for (int mt = 0; mt < 4; ++mt) af[mt] = *(const s8v*)&As[wm + mt * 16 + ln][ko];
#pragma unroll
            for (int nt = 0; nt < 4; ++nt) bf[nt] = *(const s8v*)&Bs[wn + nt * 16 + ln][ko];
#pragma unroll
            for (int mt = 0; mt < 4; ++mt)
#pragma unroll
                for (int nt = 0; nt < 4; ++nt)
                    acc[mt][nt] = __builtin_amdgcn_mfma_f32_16x16x32_bf16(af[mt], bf[nt], acc[mt][nt], 0, 0, 0);
        }
        __syncthreads();
    }

#pragma unroll
    for (int mt = 0; mt < 4; ++mt)
#pragma unroll
        for (int nt = 0; nt < 4; ++nt) {
            const int col = n0 + wn + nt * 16 + ln;
            const int row = m0 + wm + mt * 16 + quad * 4;
            const float sc = (col < 1024) ? QSCALE : 1.0f;
#pragma unroll
            for (int r = 0; r < 4; ++r)
                qkvb[(size_t)(row + r) * 3072 + col] = f2b(acc[mt][nt][r] * sc);
        }
}

// ---------------------------------------------------------------------------
// proj GEMM: [4096,1024] x [1024,1024]^T -> fp32. 64x64 tile, BK=64+swizzle.
// Grid (16,64) = 1024 blocks = 4/CU, 4 waves (2x2, each 32x32, acc 2x2 =
// 16 AGPR), LDS 16KB -> 16 waves/CU.
__global__ __launch_bounds__(256, 4) void gemm_proj(const unsigned short* __restrict__ A,
                                                    const unsigned short* __restrict__ B,
                                                    float* __restrict__ C) {
    __shared__ unsigned short As[64][64];
    __shared__ unsigned short Bs[64][64];
    const int tid = threadIdx.x;
    const int l = tid & 63, w = tid >> 6;
    const int quad = l >> 4, ln = l & 15;
    const int m0 = blockIdx.y * 64, n0 = blockIdx.x * 64;
    const int wm = (w >> 1) * 32, wn = (w & 1) * 32;

    const f4v fz = {0.f, 0.f, 0.f, 0.f};
    f4v acc[2][2];
#pragma unroll
    for (int i = 0; i < 2; ++i)
#pragma unroll
        for (int j = 0; j < 2; ++j) acc[i][j] = fz;

    // staging: 256 threads, 8 chunks/row -> 32 rows per batch, 2 batches
    const int srow = tid >> 3, sc8 = tid & 7;
    const int gcol = ((sc8 ^ (srow & 7)) << 3);
    const int koff0 = ((quad ^ (ln & 7)) << 3);
    const int koff1 = (((4 + quad) ^ (ln & 7)) << 3);

    for (int k0 = 0; k0 < 1024; k0 += 64) {
#pragma unroll
        for (int b = 0; b < 2; ++b) {
            GLD_LDS16(A + (size_t)(m0 + srow + 32 * b) * 1024 + k0 + gcol, &As[srow + 32 * b][sc8 * 8]);
            GLD_LDS16(B + (size_t)(n0 + srow + 32 * b) * 1024 + k0 + gcol, &Bs[srow + 32 * b][sc8 * 8]);
        }
        __syncthreads();
#pragma unroll
        for (int ks = 0; ks < 2; ++ks) {
            const int ko = ks ? koff1 : koff0;
            s8v af[2], bf[2];
#pragma unroll
            for (int mt = 0; mt < 2; ++mt) af[mt] = *(const s8v*)&As[wm + mt * 16 + ln][ko];
#pragma unroll
            for (int nt = 0; nt < 2; ++nt) bf[nt] = *(const s8v*)&Bs[wn + nt * 16 + ln][ko];
#pragma unroll
            for (int mt = 0; mt < 2; ++mt)
#pragma unroll
                for (int nt = 0; nt < 2; ++nt)
                    acc[mt][nt] = __builtin_amdgcn_mfma_f32_16x16x32_bf16(af[mt], bf[nt], acc[mt][nt], 0, 0, 0);
        }
        __syncthreads();
    }

#pragma unroll
    for (int mt = 0; mt < 2; ++mt)
#pragma unroll
        for (int nt = 0; nt < 2; ++nt) {
            const int row = m0 + wm + mt * 16 + quad * 4;
            const int col = n0 + wn + nt * 16 + ln;
#pragma unroll
            for (int r = 0; r < 4; ++r) C[(size_t)(row + r) * 1024 + col] = acc[mt][nt][r];
        }
}

// ---------------------------------------------------------------------------
// KV-split flash attention: grid (16 qtiles, 16 heads, 4 = bb*2+sp).
// Block = 128 q, 4 waves x 32 q. R8 dbuf, single barrier/iter.
// 4 blocks/CU: total regs <=128 (lb(256,4)); K reg-staged into PADDED
// Ks[2][64][76]; V reg-staged transpose into Vt[2][64][76].
// Per-st-half softmax (sacc live = 16). P in-register via permlane32_swap.
// setprio(1) around MFMA clusters. Unnormalized partials to workspace.
__global__ __launch_bounds__(256, 4) void attn_split(const unsigned short* __restrict__ qkvb,
                                                     float* __restrict__ opart,
                                                     float* __restrict__ lpart) {
    __shared__ unsigned short Ks[2][64][76];   // [buf][s][d]; prologue alias: Q staging
    __shared__ unsigned short Vt[2][64][76];   // [buf][d][s]

    const int tid = threadIdx.x;
    const int l = tid & 63, w = tid >> 6;
    const int m31 = l & 31, h2 = l >> 5;
    const int qw = w * 32;
    const int t0 = blockIdx.x * 128;
    const int hh = blockIdx.y;
    const int bb = blockIdx.z >> 1, sp = blockIdx.z & 1;
    const size_t rowbase = (size_t)bb * 2048;
    const int sbase = sp * 1024;
    const unsigned sel = 0x07060302u;

    // ---- prologue: stage Q coalesced -> dead Ks bufs -> register frags ----
#pragma unroll
    for (int it = 0; it < 4; ++it) {
        const int idx = tid + it * 256;
        const int qr = idx >> 3, qc = (idx & 7) * 8;
        unsigned short* dst = (qr < 64) ? &Ks[0][qr][qc] : &Ks[1][qr - 64][qc];
        *(us8*)dst = *(const us8*)(qkvb + (rowbase + t0 + qr) * 3072 + hh * 64 + qc);
    }
    __syncthreads();
    s8v qf[4];
    {
        const int qrow = qw + m31;   // wave-uniform buf select (waves 0,1 vs 2,3)
#pragma unroll
        for (int k4 = 0; k4 < 4; ++k4)
            qf[k4] = (qrow < 64) ? *(const s8v*)&Ks[0][qrow][k4 * 16 + h2 * 8]
                                 : *(const s8v*)&Ks[1][qrow - 64][k4 * 16 + h2 * 8];
    }
    __syncthreads();   // Q fully consumed before tile-0 staging overwrites Ks

    // staging coords: K rows (b128), V 4-row x 4-col transpose chunks
    const int r0 = tid >> 3, c0 = (tid & 7) * 8;
    const int va = tid >> 4, vc = tid & 15;   // s-group 4*va, d-group 4*vc

    f16v zz;
#pragma unroll
    for (int i = 0; i < 16; ++i) zz[i] = 0.f;
    f16v oacc[2];
    oacc[0] = zz; oacc[1] = zz;
    float lsum = 0.f;

    // tile 0: global -> regs -> buf0
    us8 kreg0 = *(const us8*)(qkvb + (rowbase + sbase + r0) * 3072 + 1024 + hh * 64 + c0);
    us8 kreg1 = *(const us8*)(qkvb + (rowbase + sbase + r0 + 32) * 3072 + 1024 + hh * 64 + c0);
    us4 vreg[4];
#pragma unroll
    for (int j = 0; j < 4; ++j)
        vreg[j] = *(const us4*)(qkvb + (rowbase + sbase + 4 * va + j) * 3072 + 2048 + hh * 64 + 4 * vc);
    *(us8*)&Ks[0][r0][c0] = kreg0;
    *(us8*)&Ks[0][r0 + 32][c0] = kreg1;
#pragma unroll
    for (int dd = 0; dd < 4; ++dd) {
        unsigned lo = (unsigned)vreg[0][dd] | ((unsigned)vreg[1][dd] << 16);
        unsigned hi = (unsigned)vreg[2][dd] | ((unsigned)vreg[3][dd] << 16);
        uint2 pk2; pk2.x = lo; pk2.y = hi;
        *(uint2*)&Vt[0][4 * vc + dd][4 * va] = pk2;   // Vt[d][s0..s0+3]
    }

    for (int i = 0; i < 16; ++i) {
        const int cur = i & 1;
        __syncthreads();   // buf[cur] ready; prior reads of buf[1-cur] drained

        if (i + 1 < 16) {  // issue next tile's loads; compute body covers latency
            const size_t sn = rowbase + sbase + (i + 1) * 64;
            kreg0 = *(const us8*)(qkvb + (sn + r0) * 3072 + 1024 + hh * 64 + c0);
            kreg1 = *(const us8*)(qkvb + (sn + r0 + 32) * 3072 + 1024 + hh * 64 + c0);
#pragma unroll
            for (int j = 0; j < 4; ++j)
                vreg[j] = *(const us4*)(qkvb + (sn + 4 * va + j) * 3072 + 2048 + hh * 64 + 4 * vc);
        }

        // per st-half: QK^T -> exp2 -> pack -> permlane -> PV  (sacc live = 16)
#pragma unroll
        for (int st = 0; st < 2; ++st) {
            f16v sacc = zz;
            __builtin_amdgcn_s_setprio(1);
#pragma unroll
            for (int k4 = 0; k4 < 4; ++k4) {
                s8v kf = *(const s8v*)&Ks[cur][st * 32 + m31][k4 * 16 + h2 * 8];
                sacc = __builtin_amdgcn_mfma_f32_32x32x16_bf16(kf, qf[k4], sacc, 0, 0, 0);
            }
            __builtin_amdgcn_s_setprio(0);
            unsigned wv[4][2];
#pragma unroll
            for (int g = 0; g < 4; ++g) {
                float p0 = EXP2F(sacc[g * 4 + 0]);
                float p1 = EXP2F(sacc[g * 4 + 1]);
                float p2 = EXP2F(sacc[g * 4 + 2]);
                float p3 = EXP2F(sacc[g * 4 + 3]);
                lsum += (p0 + p1) + (p2 + p3);
                wv[g][0] = packtrunc(p0, p1, sel);
                wv[g][1] = packtrunc(p2, p3, sel);
            }
            __builtin_amdgcn_s_setprio(1);
#pragma unroll
            for (int e = 0; e < 2; ++e) {
                auto ra = __builtin_amdgcn_permlane32_swap(wv[2 * e][0], wv[2 * e + 1][0], false, false);
                auto rb = __builtin_amdgcn_permlane32_swap(wv[2 * e][1], wv[2 * e + 1][1], false, false);
                u4v t;
                t[0] = ra[0]; t[1] = rb[0];   // j0..3 (source low half)
                t[2] = ra[1]; t[3] = rb[1];   // j4..7 (source high half)
                s8v pf = __builtin_bit_cast(s8v, t);
                const int k2 = 2 * st + e;
#pragma unroll
                for (int nt = 0; nt < 2; ++nt) {
                    s8v vfr = *(const s8v*)&Vt[cur][nt * 32 + m31][k2 * 16 + h2 * 8];
                    oacc[nt] = __builtin_amdgcn_mfma_f32_32x32x16_bf16(pf, vfr, oacc[nt], 0, 0, 0);
                }
            }
            __builtin_amdgcn_s_setprio(0);
        }

        if (i + 1 < 16) {  // stage tile i+1 into the other buffer (tail; no barrier)
            *(us8*)&Ks[1 - cur][r0][c0] = kreg0;
            *(us8*)&Ks[1 - cur][r0 + 32][c0] = kreg1;
#pragma unroll
            for (int dd = 0; dd < 4; ++dd) {
                unsigned lo = (unsigned)vreg[0][dd] | ((unsigned)vreg[1][dd] << 16);
                unsigned hi = (unsigned)vreg[2][dd] | ((unsigned)vreg[3][dd] << 16);
                uint2 pk2; pk2.x = lo; pk2.y = hi;
                *(uint2*)&Vt[1 - cur][4 * vc + dd][4 * va] = pk2;
            }
        }
    }

    // partial l per q (lanes l and l+32 hold halves of the same q-row)
    lsum += __shfl_xor(lsum, 32, 64);
    if (h2 == 0)
        lpart[((size_t)sp * 4096 + rowbase + t0 + qw + m31) * 16 + hh] = lsum;

    // epilogue: UNNORMALIZED fp32 partial O.  col d = m31 (+32*nt), row q = 8g+4h2+r
    float* op = opart + (size_t)sp * 4096 * 1024;
#pragma unroll
    for (int nt = 0; nt < 2; ++nt)
#pragma unroll
        for (int g = 0; g < 4; ++g)
#pragma unroll
            for (int r = 0; r < 4; ++r) {
                const int qrow = 8 * g + 4 * h2 + r;
                op[(rowbase + t0 + qw + qrow) * 1024 + hh * 64 + nt * 32 + m31] = oacc[nt][g * 4 + r];
            }
}

// attnb[r][c] = f2b((O0+O1) * 1.001955/(l0+l1)).  1M threads, 4 cols each.
__global__ __launch_bounds__(256) void attn_combine(const float* __restrict__ opart,
                                                    const float* __restrict__ lpart,
                                                    unsigned short* __restrict__ attnb) {
    const int idx = blockIdx.x * 256 + threadIdx.x;
    const int r = idx >> 8, c4 = (idx & 255) << 2, h = c4 >> 6;
    const size_t fi = (size_t)r * 256 + (c4 >> 2);
    float4 o0 = ((const float4*)opart)[fi];
    float4 o1 = ((const float4*)(opart + (size_t)4096 * 1024))[fi];
    float ls = lpart[(size_t)r * 16 + h] + lpart[((size_t)4096 + r) * 16 + h];
    float s = 1.001955f / ls;   // (1+2^-9) compensates P truncation bias
    ushort4 o;
    o.x = f2b((o0.x + o1.x) * s);
    o.y = f2b((o0.y + o1.y) * s);
    o.z = f2b((o0.z + o1.z) * s);
    o.w = f2b((o0.w + o1.w) * s);
    ((ushort4*)attnb)[fi] = o;
}

// ---------------------------------------------------------------------------
// Fallback single-pass attention (normalizes in-kernel). Used when ws_size
// can't hold the split partials.
__global__ __launch_bounds__(256) void attn_mfma(const unsigned short* __restrict__ qkvb,
                                                 unsigned short* __restrict__ attnb) {
    __shared__ unsigned short Ks[2][64][76];
    __shared__ unsigned short Vt[2][64][76];
    __shared__ float lred[128];

    const int tid = threadIdx.x;
    const int l = tid & 63, w = tid >> 6;
    const int m31 = l & 31, h2 = l >> 5;
    const int qw = w * 32;
    const int t0 = blockIdx.x * 128;
    const int hh = blockIdx.y, bb = blockIdx.z;
    const size_t rowbase = (size_t)bb * 2048;
    const unsigned sel = 0x07060302u;

#pragma unroll
    for (int it = 0; it < 4; ++it) {
        const int idx = tid + it * 256;
        const int qr = idx >> 3, qc = (idx & 7) * 8;
        unsigned short* dst = (qr < 64) ? &Ks[0][qr][qc] : &Ks[1][qr - 64][qc];
        *(us8*)dst = *(const us8*)(qkvb + (rowbase + t0 + qr) * 3072 + hh * 64 + qc);
    }
    __syncthreads();
    s8v qf[4];
    {
        const int qrow = qw + m31;
#pragma unroll
        for (int k4 = 0; k4 < 4; ++k4)
            qf[k4] = (qrow < 64) ? *(const s8v*)&Ks[0][qrow][k4 * 16 + h2 * 8]
                                 : *(const s8v*)&Ks[1][qrow - 64][k4 * 16 + h2 * 8];
    }
    __syncthreads();

    const int r0 = tid >> 3, c0 = (tid & 7) * 8;
    const int va = tid >> 4, vc = tid & 15;

    f16v zz;
#pragma unroll
    for (int i = 0; i < 16; ++i) zz[i] = 0.f;
    f16v oacc[2];
    oacc[0] = zz; oacc[1] = zz;
    float lsum = 0.f;

    us8 kreg0 = *(const us8*)(qkvb + (rowbase + r0) * 3072 + 1024 + hh * 64 + c0);
    us8 kreg1 = *(const us8*)(qkvb + (rowbase + r0 + 32) * 3072 + 1024 + hh * 64 + c0);
    us4 vreg[4];
#pragma unroll
    for (int j = 0; j < 4; ++j)
        vreg[j] = *(const us4*)(qkvb + (rowbase + 4 * va + j) * 3072 + 2048 + hh * 64 + 4 * vc);
    *(us8*)&Ks[0][r0][c0] = kreg0;
    *(us8*)&Ks[0][r0 + 32][c0] = kreg1;
#pragma unroll
    for (int dd = 0; dd < 4; ++dd) {
        unsigned lo = (unsigned)vreg[0][dd] | ((unsigned)vreg[1][dd] << 16);
        unsigned hi = (unsigned)vreg[2][dd] | ((unsigned)vreg[3][dd] << 16);
        uint2 pk2; pk2.x = lo; pk2.y = hi;
        *(uint2*)&Vt[0][4 * vc + dd][4 * va] = pk2;
    }

    for (int i = 0; i < 32; ++i) {
        const int cur = i & 1;
        __syncthreads();

        if (i + 1 < 32) {
            const int sn = (i + 1) * 64;
            kreg0 = *(const us8*)(qkvb + (rowbase + sn + r0) * 3072 + 1024 + hh * 64 + c0);
            kreg1 = *(const us8*)(qkvb + (rowbase + sn + r0 + 32) * 3072 + 1024 + hh * 64 + c0);
#pragma unroll
            for (int j = 0; j < 4; ++j)
                vreg[j] = *(const us4*)(qkvb + (rowbase + sn + 4 * va + j) * 3072 + 2048 + hh * 64 + 4 * vc);
        }

        f16v sacc[2];
        sacc[0] = zz; sacc[1] = zz;
#pragma unroll
        for (int k4 = 0; k4 < 4; ++k4) {
#pragma unroll
            for (int st = 0; st < 2; ++st) {
                s8v kf = *(const s8v*)&Ks[cur][st * 32 + m31][k4 * 16 + h2 * 8];
                sacc[st] = __builtin_amdgcn_mfma_f32_32x32x16_bf16(kf, qf[k4], sacc[st], 0, 0, 0);
            }
        }

        unsigned wv[2][4][2];
#pragma unroll
        for (int st = 0; st < 2; ++st)
#pragma unroll
            for (int g = 0; g < 4; ++g) {
                float p0 = EXP2F(sacc[st][g * 4 + 0]);
                float p1 = EXP2F(sacc[st][g * 4 + 1]);
                float p2 = EXP2F(sacc[st][g * 4 + 2]);
                float p3 = EXP2F(sacc[st][g * 4 + 3]);
                lsum += (p0 + p1) + (p2 + p3);
                wv[st][g][0] = packtrunc(p0, p1, sel);
                wv[st][g][1] = packtrunc(p2, p3, sel);
            }

        s8v pf[4];
#pragma unroll
        for (int st = 0; st < 2; ++st)
#pragma unroll
            for (int e = 0; e < 2; ++e) {
                auto ra = __builtin_amdgcn_permlane32_swap(wv[st][2 * e][0], wv[st][2 * e + 1][0], false, false);
                auto rb = __builtin_amdgcn_permlane32_swap(wv[st][2 * e][1], wv[st][2 * e + 1][1], false, false);
                u4v t;
                t[0] = ra[0]; t[1] = rb[0];
                t[2] = ra[1]; t[3] = rb[1];
                pf[2 * st + e] = __builtin_bit_cast(s8v, t);
            }

#pragma unroll
        for (int k2 = 0; k2 < 4; ++k2) {
#pragma unroll
            for (int nt = 0; nt < 2; ++nt) {
                s8v vfr = *(const s8v*)&Vt[cur][nt * 32 + m31][k2 * 16 + h2 * 8];
                oacc[nt] = __builtin_amdgcn_mfma_f32_32x32x16_bf16(pf[k2], vfr, oacc[nt], 0, 0, 0);
            }
        }

        if (i + 1 < 32) {
            *(us8*)&Ks[1 - cur][r0][c0] = kreg0;
            *(us8*)&Ks[1 - cur][r0 + 32][c0] = kreg1;
#pragma unroll
            for (int dd = 0; dd < 4; ++dd) {
                unsigned lo = (unsigned)vreg[0][dd] | ((unsigned)vreg[1][dd] << 16);
                unsigned hi = (unsigned)vreg[2][dd] | ((unsigned)vreg[3][dd] << 16);
                uint2 pk2; pk2.x = lo; pk2.y = hi;
                *(uint2*)&Vt[1 - cur][4 * vc + dd][4 * va] = pk2;
            }
        }
    }

    lsum += __shfl_xor(lsum, 32, 64);
    lred[qw + m31] = lsum;
    float inv[16];
#pragma unroll
    for (int g = 0; g < 4; ++g)
#pragma unroll
        for (int r = 0; r < 4; ++r)
            inv[g * 4 + r] = 1.001955f / lred[qw + 8 * g + 4 * h2 + r];

#pragma unroll
    for (int nt = 0; nt < 2; ++nt)
#pragma unroll
        for (int g = 0; g < 4; ++g)
#pragma unroll
            for (int r = 0; r < 4; ++r) {
                const int qrow = 8 * g + 4 * h2 + r;
                float o = oacc[nt][g * 4 + r] * inv[g * 4 + r];
                attnb[(rowbase + t0 + qw + qrow) * 1024 + hh * 64 + nt * 32 + m31] = f2b(o);
            }
}

// ---------------------------------------------------------------------------
extern "C" void kernel_launch(void* const* d_in, const int* in_sizes, int n_in,
                              void* d_out, int out_size, void* d_ws, size_t ws_size,
                              hipStream_t stream) {
    const float* x      = (const float*)d_in[0];   // [4096,1024]
    const float* w_qkv  = (const float*)d_in[1];   // [3072,1024]
    const float* w_proj = (const float*)d_in[2];   // [1024,1024]
    float* out = (float*)d_out;

    char* p = (char*)d_ws;
    unsigned short* xb    = (unsigned short*)p;  p += (size_t)4096 * 1024 * 2;
    unsigned short* wqb   = (unsigned short*)p;  p += (size_t)3072 * 1024 * 2;
    unsigned short* wpb   = (unsigned short*)p;  p += (size_t)1024 * 1024 * 2;
    unsigned short* qkvb  = (unsigned short*)p;  p += (size_t)4096 * 3072 * 2;
    unsigned short* attnb = (unsigned short*)p;  p += (size_t)4096 * 1024 * 2;
    float* opart = (float*)p;  p += (size_t)2 * 4096 * 1024 * 4;   // 32 MB
    float* lpart = (float*)p;  p += (size_t)2 * 4096 * 16 * 4;     // 0.5 MB
    const size_t need = (size_t)(p - (char*)d_ws);

    cvt_all<<<8192, 256, 0, stream>>>(x, w_qkv, w_proj, xb, wqb, wpb);

    gemm_qkv<<<dim3(3072 / 128, 4096 / 128), 256, 0, stream>>>(xb, wqb, qkvb);

    if (ws_size >= need) {
        attn_split<<<dim3(2048 / 128, 16, 4), 256, 0, stream>>>(qkvb, opart, lpart);
        attn_combine<<<4096, 256, 0, stream>>>(opart, lpart, attnb);
    } else {
        attn_mfma<<<dim3(2048 / 128, 16, 2), 256, 0, stream>>>(qkvb, attnb);
    }

    gemm_proj<<<dim3(1024 / 64, 4096 / 64), 256, 0, stream>>>(attnb, wpb, out);
}